// Round 2
// baseline (767.977 us; speedup 1.0000x reference)
//
#include <hip/hip_runtime.h>
#include <hip/hip_bf16.h>

// Problem constants (fixed by the reference file).
#define K_OFF 27
#define M_PTS 100000
#define KM (K_OFF * M_PTS)      // 2,700,000 contributions
#define C_CH 64
#define N_OUT_PTS 400000
#define BN_EPS 1e-5f

#define TILE_PTS 16
#define NT (M_PTS / TILE_PTS)   // 6250 tiles per k-offset
#define BLKX 64                 // blocks.x per k for the dense GEMM
#define WSTRIDE (BLKX * 4)
#define CAP 40                  // bin capacity; Poisson(6.75) tail P(>=40) ~ 1e-18

typedef __attribute__((ext_vector_type(8))) short short8;  // 8 bf16 = 4 VGPRs
typedef __attribute__((ext_vector_type(4))) float f32x4;

__device__ inline short bf16c(float f) {
    return __builtin_bit_cast(short, __float2bfloat16(f));
}
__device__ inline float b2f(unsigned short u) {
    return __builtin_bit_cast(float, (unsigned)u << 16);
}

// Packed 2xbf16 atomic add (fallback path only).
__device__ inline void pk_atomic_add_bf16(__hip_bfloat16* p, int bits) {
#if __has_builtin(__builtin_amdgcn_global_atomic_fadd_v2bf16)
    typedef short s2v __attribute__((ext_vector_type(2)));
    typedef __attribute__((address_space(1))) s2v* gp;
    s2v v;
    __builtin_memcpy(&v, &bits, 4);
    __builtin_amdgcn_global_atomic_fadd_v2bf16((gp)(unsigned long long)p, v);
#else
    asm volatile("global_atomic_pk_add_bf16 %0, %1, off"
                 :: "v"((unsigned long long)p), "v"(bits) : "memory");
#endif
}

// ---------------------------------------------------------------------------
// Shared MFMA core: staged fp32 rows -> A frags, 8x mfma_f32_16x16x32_bf16.
// Lane l (g=l>>4, c=l&15): D layout col=c (N-tile tt -> cout 4c+tt),
// row=4g+reg. Lane l's acc[0..3][e] = couts 4c..4c+3 of tile point 4g+e.
// ---------------------------------------------------------------------------
__device__ __attribute__((always_inline)) inline void tile_mfma(
    const float4* cur, const short8 bfrag[2][4], f32x4 acc[4])
{
    short8 af0, af1;
    #pragma unroll
    for (int j = 0; j < 4; ++j) {
        af0[j]     = bf16c(cur[0][j]);
        af0[j + 4] = bf16c(cur[1][j]);
        af1[j]     = bf16c(cur[2][j]);
        af1[j + 4] = bf16c(cur[3][j]);
    }
    #pragma unroll
    for (int tt = 0; tt < 4; ++tt) {
        f32x4 z = {0.f, 0.f, 0.f, 0.f};
        z       = __builtin_amdgcn_mfma_f32_16x16x32_bf16(af0, bfrag[0][tt], z, 0, 0, 0);
        acc[tt] = __builtin_amdgcn_mfma_f32_16x16x32_bf16(af1, bfrag[1][tt], z, 0, 0, 0);
    }
}

__device__ __attribute__((always_inline)) inline void load_bfrag(
    const float* __restrict__ Wk, int g, int c, short8 bfrag[2][4])
{
    #pragma unroll
    for (int s = 0; s < 2; ++s) {
        #pragma unroll
        for (int tt = 0; tt < 4; ++tt) {
            short8 v;
            #pragma unroll
            for (int j = 0; j < 8; ++j)
                v[j] = bf16c(Wk[(size_t)(32 * s + 8 * g + j) * C_CH + 4 * c + tt]);
            bfrag[s][tt] = v;
        }
    }
}

// ===========================================================================
// DENSE PATH (no scatter atomics):
//   bin_fill -> contrib_gemm (dense bf16 contrib) -> gather_bn -> bn_apply_f32
// ===========================================================================

// Bucket contribution ids by destination row. 2.7M int atomics total.
__global__ __launch_bounds__(256) void bin_fill(
    const int* __restrict__ out_idx, int* __restrict__ counts,
    int* __restrict__ entries)
{
    int i = blockIdx.x * 256 + threadIdx.x;
    if (i >= KM) return;
    int o = out_idx[i];
    int pos = atomicAdd(&counts[o], 1);
    if (pos < CAP) entries[(size_t)o * CAP + pos] = i;
}

// Dense contribution GEMM: gather x rows, MFMA, LINEAR 128B-per-point stores.
__global__ __launch_bounds__(256, 4) void contrib_gemm(
    const float* __restrict__ x, const float* __restrict__ W,
    const int* __restrict__ in_idx, unsigned short* __restrict__ contrib)
{
    const int k = blockIdx.y;
    const int lane = threadIdx.x & 63;
    const int wave = threadIdx.x >> 6;
    const int g = lane >> 4;
    const int c = lane & 15;

    short8 bfrag[2][4];
    load_bfrag(W + (size_t)k * C_CH * C_CH, g, c, bfrag);

    const int kbase = k * M_PTS;
    const int t0 = blockIdx.x * 4 + wave;   // 0..255 < NT

    int src_c = in_idx[kbase + t0 * TILE_PTS + c];
    float4 cur[4];
    {
        const float4* xr = (const float4*)x + (size_t)src_c * 16;
        cur[0] = xr[2 * g];     cur[1] = xr[2 * g + 1];      // cin 8g..8g+7
        cur[2] = xr[8 + 2 * g]; cur[3] = xr[8 + 2 * g + 1];  // cin 32+8g..
    }
    int src_n = (t0 + WSTRIDE < NT) ? in_idx[kbase + (t0 + WSTRIDE) * TILE_PTS + c] : 0;

    int t = t0;
    for (; t + WSTRIDE < NT; t += WSTRIDE) {
        const int tn = t + WSTRIDE;
        float4 nxt[4];
        {
            const float4* xr = (const float4*)x + (size_t)src_n * 16;
            nxt[0] = xr[2 * g];     nxt[1] = xr[2 * g + 1];
            nxt[2] = xr[8 + 2 * g]; nxt[3] = xr[8 + 2 * g + 1];
        }
        const int t2 = tn + WSTRIDE;
        const int src_2 = (t2 < NT) ? in_idx[kbase + t2 * TILE_PTS + c] : 0;

        f32x4 acc[4];
        tile_mfma(cur, bfrag, acc);
        const size_t ebase = (size_t)(kbase + t * TILE_PTS);
        #pragma unroll
        for (int e = 0; e < 4; ++e) {
            union { __hip_bfloat162 h; unsigned u; } p0, p1;
            p0.h = __hip_bfloat162(__float2bfloat16(acc[0][e]), __float2bfloat16(acc[1][e]));
            p1.h = __hip_bfloat162(__float2bfloat16(acc[2][e]), __float2bfloat16(acc[3][e]));
            uint2 wv; wv.x = p0.u; wv.y = p1.u;
            *(uint2*)(contrib + (ebase + 4 * g + e) * C_CH + 4 * c) = wv;
        }

        #pragma unroll
        for (int j = 0; j < 4; ++j) cur[j] = nxt[j];
        src_n = src_2;
    }
    // epilogue tile
    {
        f32x4 acc[4];
        tile_mfma(cur, bfrag, acc);
        const size_t ebase = (size_t)(kbase + t * TILE_PTS);
        #pragma unroll
        for (int e = 0; e < 4; ++e) {
            union { __hip_bfloat162 h; unsigned u; } p0, p1;
            p0.h = __hip_bfloat162(__float2bfloat16(acc[0][e]), __float2bfloat16(acc[1][e]));
            p1.h = __hip_bfloat162(__float2bfloat16(acc[2][e]), __float2bfloat16(acc[3][e]));
            uint2 wv; wv.x = p0.u; wv.y = p1.u;
            *(uint2*)(contrib + (ebase + 4 * g + e) * C_CH + 4 * c) = wv;
        }
    }
}

// Per-output-row gather-sum (fp32) + fused BN statistics.
// Wave layout: g=lane>>4 picks 1 of 4 independent rows (MLP), c4=lane&15
// owns channels 4c4..4c4+3 (ushort4 = 8B -> 16 lanes = 128B coalesced row).
__global__ __launch_bounds__(256) void gather_bn(
    const unsigned short* __restrict__ contrib, const int* __restrict__ counts,
    const int* __restrict__ entries, float* __restrict__ preact,
    float* __restrict__ stats)
{
    const int lane = threadIdx.x & 63;
    const int wave = threadIdx.x >> 6;
    const int g = lane >> 4;
    const int c4 = lane & 15;

    float s0 = 0.f, s1 = 0.f, s2 = 0.f, s3 = 0.f;
    float q0 = 0.f, q1 = 0.f, q2 = 0.f, q3 = 0.f;

    for (int r = blockIdx.x * 16 + wave * 4 + g; r < N_OUT_PTS; r += gridDim.x * 16) {
        int cnt = counts[r];
        cnt = cnt > CAP ? CAP : cnt;
        const int* ep = entries + (size_t)r * CAP;
        float a0 = 0.f, a1 = 0.f, a2 = 0.f, a3 = 0.f;
        for (int j = 0; j < cnt; ++j) {
            int e = ep[j];
            ushort4 v = *(const ushort4*)(contrib + (size_t)e * C_CH + 4 * c4);
            a0 += b2f(v.x); a1 += b2f(v.y); a2 += b2f(v.z); a3 += b2f(v.w);
        }
        float4 w; w.x = a0; w.y = a1; w.z = a2; w.w = a3;
        *(float4*)(preact + (size_t)r * C_CH + 4 * c4) = w;
        s0 += a0; s1 += a1; s2 += a2; s3 += a3;
        q0 += a0 * a0; q1 += a1 * a1; q2 += a2 * a2; q3 += a3 * a3;
    }

    __shared__ float sh[2][256][4];
    sh[0][threadIdx.x][0] = s0; sh[0][threadIdx.x][1] = s1;
    sh[0][threadIdx.x][2] = s2; sh[0][threadIdx.x][3] = s3;
    sh[1][threadIdx.x][0] = q0; sh[1][threadIdx.x][1] = q1;
    sh[1][threadIdx.x][2] = q2; sh[1][threadIdx.x][3] = q3;
    __syncthreads();
    if (threadIdx.x < C_CH) {
        const int ch = threadIdx.x;
        const int cc = ch >> 2, jj = ch & 3;
        float ts = 0.f, tq = 0.f;
        #pragma unroll
        for (int u = 0; u < 16; ++u) {
            ts += sh[0][16 * u + cc][jj];
            tq += sh[1][16 * u + cc][jj];
        }
        unsafeAtomicAdd(&stats[ch], ts);
        unsafeAtomicAdd(&stats[C_CH + ch], tq);
    }
}

// In-place BN+ReLU on fp32 preact (= d_out).
__global__ __launch_bounds__(256) void bn_apply_f32(
    float* __restrict__ out, const float* __restrict__ stats,
    const float* __restrict__ gamma, const float* __restrict__ beta)
{
    const float inv_n = 1.0f / (float)N_OUT_PTS;
    const int c0 = 8 * (threadIdx.x & 7);
    float sc[8], bs[8];
    #pragma unroll
    for (int j = 0; j < 8; ++j) {
        int ch = c0 + j;
        float mean = stats[ch] * inv_n;
        float var = stats[C_CH + ch] * inv_n - mean * mean;
        float s = gamma[ch] * rsqrtf(var + BN_EPS);
        sc[j] = s;
        bs[j] = beta[ch] - mean * s;
    }
    float4* o4 = (float4*)out;
    const size_t n = (size_t)N_OUT_PTS * C_CH / 8;
    const size_t stride = (size_t)gridDim.x * blockDim.x;
    for (size_t i = (size_t)blockIdx.x * blockDim.x + threadIdx.x; i < n; i += stride) {
        float4 r0 = o4[2 * i], r1 = o4[2 * i + 1];
        r0.x = fmaxf(fmaf(r0.x, sc[0], bs[0]), 0.f);
        r0.y = fmaxf(fmaf(r0.y, sc[1], bs[1]), 0.f);
        r0.z = fmaxf(fmaf(r0.z, sc[2], bs[2]), 0.f);
        r0.w = fmaxf(fmaf(r0.w, sc[3], bs[3]), 0.f);
        r1.x = fmaxf(fmaf(r1.x, sc[4], bs[4]), 0.f);
        r1.y = fmaxf(fmaf(r1.y, sc[5], bs[5]), 0.f);
        r1.z = fmaxf(fmaf(r1.z, sc[6], bs[6]), 0.f);
        r1.w = fmaxf(fmaf(r1.w, sc[7], bs[7]), 0.f);
        o4[2 * i] = r0;
        o4[2 * i + 1] = r1;
    }
}

// ===========================================================================
// FALLBACK PATH (ws too small): round-1 atomic scatter pipeline, proven pass.
// ===========================================================================
__global__ __launch_bounds__(256, 4) void scatter_gemm_fb(
    const float* __restrict__ x, const float* __restrict__ W,
    const int* __restrict__ in_idx, const int* __restrict__ out_idx,
    __hip_bfloat16* __restrict__ out_ws)
{
    const int k = blockIdx.y;
    const int lane = threadIdx.x & 63;
    const int wave = threadIdx.x >> 6;
    const int g = lane >> 4;
    const int c = lane & 15;

    short8 bfrag[2][4];
    load_bfrag(W + (size_t)k * C_CH * C_CH, g, c, bfrag);

    const int kbase = k * M_PTS;
    for (int t = blockIdx.x * 4 + wave; t < NT; t += WSTRIDE) {
        int src = in_idx[kbase + t * TILE_PTS + c];
        float4 cur[4];
        const float4* xr = (const float4*)x + (size_t)src * 16;
        cur[0] = xr[2 * g];     cur[1] = xr[2 * g + 1];
        cur[2] = xr[8 + 2 * g]; cur[3] = xr[8 + 2 * g + 1];
        int dstv[4];
        #pragma unroll
        for (int e = 0; e < 4; ++e)
            dstv[e] = out_idx[kbase + t * TILE_PTS + 4 * g + e];
        f32x4 acc[4];
        tile_mfma(cur, bfrag, acc);
        #pragma unroll
        for (int e = 0; e < 4; ++e) {
            __hip_bfloat16* rp = out_ws + (size_t)dstv[e] * C_CH + 4 * c;
            union { __hip_bfloat162 h; int i; } p0, p1;
            p0.h = __hip_bfloat162(__float2bfloat16(acc[0][e]), __float2bfloat16(acc[1][e]));
            p1.h = __hip_bfloat162(__float2bfloat16(acc[2][e]), __float2bfloat16(acc[3][e]));
            pk_atomic_add_bf16(rp, p0.i);
            pk_atomic_add_bf16(rp + 2, p1.i);
        }
    }
}

__global__ __launch_bounds__(256) void bn_stats_fb(
    const __hip_bfloat16* __restrict__ ws, float* __restrict__ stats)
{
    const uint4* in = (const uint4*)ws;
    const size_t n = (size_t)N_OUT_PTS * C_CH / 8;
    const size_t stride = (size_t)gridDim.x * blockDim.x;
    float s[8], s2[8];
    #pragma unroll
    for (int j = 0; j < 8; ++j) { s[j] = 0.f; s2[j] = 0.f; }
    for (size_t i = (size_t)blockIdx.x * blockDim.x + threadIdx.x; i < n; i += stride) {
        uint4 q = in[i];
        unsigned wds[4] = {q.x, q.y, q.z, q.w};
        #pragma unroll
        for (int j = 0; j < 4; ++j) {
            __hip_bfloat162 h = *(__hip_bfloat162*)&wds[j];
            float f0 = __low2float(h), f1 = __high2float(h);
            s[2 * j] += f0;  s2[2 * j] += f0 * f0;
            s[2 * j + 1] += f1; s2[2 * j + 1] += f1 * f1;
        }
    }
    __shared__ float sh[2][256][8];
    #pragma unroll
    for (int j = 0; j < 8; ++j) { sh[0][threadIdx.x][j] = s[j]; sh[1][threadIdx.x][j] = s2[j]; }
    __syncthreads();
    if (threadIdx.x < C_CH) {
        const int c = threadIdx.x;
        float ts = 0.f, t2 = 0.f;
        #pragma unroll
        for (int q = 0; q < 32; ++q) {
            ts += sh[0][8 * q + (c >> 3)][c & 7];
            t2 += sh[1][8 * q + (c >> 3)][c & 7];
        }
        unsafeAtomicAdd(&stats[c], ts);
        unsafeAtomicAdd(&stats[C_CH + c], t2);
    }
}

__global__ __launch_bounds__(256) void bn_apply_fb(
    const __hip_bfloat16* __restrict__ ws, const float* __restrict__ stats,
    const float* __restrict__ gamma, const float* __restrict__ beta,
    float* __restrict__ out)
{
    const float inv_n = 1.0f / (float)N_OUT_PTS;
    const int c0 = 8 * (threadIdx.x & 7);
    float sc[8], bs[8];
    #pragma unroll
    for (int j = 0; j < 8; ++j) {
        int c = c0 + j;
        float mean = stats[c] * inv_n;
        float var = stats[C_CH + c] * inv_n - mean * mean;
        float s = gamma[c] * rsqrtf(var + BN_EPS);
        sc[j] = s;
        bs[j] = beta[c] - mean * s;
    }
    const uint4* in = (const uint4*)ws;
    float4* o4 = (float4*)out;
    const size_t n = (size_t)N_OUT_PTS * C_CH / 8;
    const size_t stride = (size_t)gridDim.x * blockDim.x;
    for (size_t i = (size_t)blockIdx.x * blockDim.x + threadIdx.x; i < n; i += stride) {
        uint4 q = in[i];
        unsigned wds[4] = {q.x, q.y, q.z, q.w};
        float f[8];
        #pragma unroll
        for (int j = 0; j < 4; ++j) {
            __hip_bfloat162 h = *(__hip_bfloat162*)&wds[j];
            f[2 * j] = __low2float(h);
            f[2 * j + 1] = __high2float(h);
        }
        float4 r0, r1;
        r0.x = fmaxf(fmaf(f[0], sc[0], bs[0]), 0.f);
        r0.y = fmaxf(fmaf(f[1], sc[1], bs[1]), 0.f);
        r0.z = fmaxf(fmaf(f[2], sc[2], bs[2]), 0.f);
        r0.w = fmaxf(fmaf(f[3], sc[3], bs[3]), 0.f);
        r1.x = fmaxf(fmaf(f[4], sc[4], bs[4]), 0.f);
        r1.y = fmaxf(fmaf(f[5], sc[5], bs[5]), 0.f);
        r1.z = fmaxf(fmaf(f[6], sc[6], bs[6]), 0.f);
        r1.w = fmaxf(fmaf(f[7], sc[7], bs[7]), 0.f);
        o4[2 * i] = r0;
        o4[2 * i + 1] = r1;
    }
}

extern "C" void kernel_launch(void* const* d_in, const int* in_sizes, int n_in,
                              void* d_out, int out_size, void* d_ws, size_t ws_size,
                              hipStream_t stream) {
    const float* x      = (const float*)d_in[0];
    const float* W      = (const float*)d_in[1];
    const float* gamma  = (const float*)d_in[2];
    const float* beta   = (const float*)d_in[3];
    const int*   in_idx = (const int*)d_in[4];
    const int*   out_idx= (const int*)d_in[5];
    float* out = (float*)d_out;

    // Dense-path workspace layout (all offsets 256B-aligned):
    const size_t CONTRIB_B = (size_t)KM * C_CH * 2;            // 345,600,000
    const size_t COUNTS_B  = (size_t)N_OUT_PTS * 4;            //   1,600,000
    const size_t ENTRIES_B = (size_t)N_OUT_PTS * CAP * 4;      //  64,000,000
    const size_t STATS_B   = 2 * C_CH * sizeof(float);
    const size_t NEEDED = CONTRIB_B + COUNTS_B + ENTRIES_B + STATS_B;

    if (ws_size >= NEEDED) {
        unsigned short* contrib = (unsigned short*)d_ws;
        int* counts = (int*)((char*)d_ws + CONTRIB_B);
        int* entries = (int*)((char*)d_ws + CONTRIB_B + COUNTS_B);
        float* stats = (float*)((char*)d_ws + CONTRIB_B + COUNTS_B + ENTRIES_B);

        (void)hipMemsetAsync(counts, 0, COUNTS_B, stream);
        (void)hipMemsetAsync(stats, 0, STATS_B, stream);

        bin_fill<<<(KM + 255) / 256, 256, 0, stream>>>(out_idx, counts, entries);
        contrib_gemm<<<dim3(BLKX, K_OFF), 256, 0, stream>>>(x, W, in_idx, contrib);
        gather_bn<<<12800, 256, 0, stream>>>(contrib, counts, entries, out, stats);
        bn_apply_f32<<<2048, 256, 0, stream>>>(out, stats, gamma, beta);
    } else {
        // Fallback: atomic-scatter pipeline (fits in ~53 MB of ws).
        __hip_bfloat16* out_ws = (__hip_bfloat16*)d_ws;
        const size_t acc_elems = (size_t)N_OUT_PTS * C_CH;
        float* stats = (float*)((char*)d_ws + acc_elems * sizeof(__hip_bfloat16));
        const size_t clear_bytes = acc_elems * sizeof(__hip_bfloat16) + STATS_B;
        (void)hipMemsetAsync(d_ws, 0, clear_bytes, stream);

        scatter_gemm_fb<<<dim3(BLKX, K_OFF), 256, 0, stream>>>(x, W, in_idx, out_idx, out_ws);
        bn_stats_fb<<<2048, 256, 0, stream>>>(out_ws, stats);
        bn_apply_fb<<<2048, 256, 0, stream>>>(out_ws, stats, gamma, beta, out);
    }
}